// Round 10
// baseline (178.181 us; speedup 1.0000x reference)
//
#include <hip/hip_runtime.h>
#include <hip/hip_bf16.h>
#include <cmath>

typedef __attribute__((ext_vector_type(4))) float f32x4;
typedef __attribute__((ext_vector_type(8))) short s16x8;
typedef __attribute__((ext_vector_type(4))) short s16x4;
typedef __attribute__((ext_vector_type(4))) unsigned short u16x4;

static constexpr int NCOL = 512;    // L
static constexpr int NBATCH = 1024; // 32*32
static constexpr int SLOT = 64 * NCOL;     // floats per batch slot

__device__ inline unsigned short bf16h(float f) {
  return __builtin_bit_cast(unsigned short, __float2bfloat16(f));
}
__device__ inline float bf16f(unsigned short h) {
  unsigned u = ((unsigned)h) << 16;
  return __builtin_bit_cast(float, u);
}

// 8B-aligned s16x8 load (XT rows at stride 68 ushorts are only 8B-aligned)
__device__ inline s16x8 ld8(const unsigned short* p) {
  const s16x4 a = *(const s16x4*)(p);
  const s16x4 b = *(const s16x4*)(p + 4);
  s16x8 r;
  r[0]=a[0]; r[1]=a[1]; r[2]=a[2]; r[3]=a[3];
  r[4]=b[0]; r[5]=b[1]; r[6]=b[2]; r[7]=b[3];
  return r;
}

// bf16 hi/lo staging buffers (gram phase) overlaid by G/Cs f32 matrix
// (solve phase) -> T hi/lo planes (emit).  18432 B total.
union GramLds {
  struct { unsigned short Hs[64][72]; unsigned short Ls[64][72]; } s; // 18432 B
  float GW[64][68];                                                  // 17408 B
};

// Kernel 1: per-batch G = X X^T via bf16 hi/lo MFMA (G kept in LDS), then
// waves 1-3 exit and wave 0 runs the register LDL -> scaled coeffs Cs (in
// place over G) -> register triangular inverse -> emits
// T = diag(1/sqrt(n)) * (I+C)^{-1} PLANAR bf16 hi/lo to the slot head
// (u16 [0,4096) = Th, [4096,8192) = Tl).  No global G roundtrip.
__global__ __launch_bounds__(256, 4) void gs_gram_solve_kernel(const float* __restrict__ x,
                                                               float* __restrict__ outbuf)
{
  __shared__ GramLds U;
  __shared__ float ISN[64];

  const int b = blockIdx.x;
  const int t = threadIdx.x;
  const int lane = t & 63;
  const int w = t >> 6;

  const float* __restrict__ X = x + (size_t)b * SLOT;

  f32x4 acc[4];
#pragma unroll
  for (int q = 0; q < 4; ++q) { acc[q][0] = 0.f; acc[q][1] = 0.f; acc[q][2] = 0.f; acc[q][3] = 0.f; }

  const int lrow = t >> 4;               // 0..15 staging row base
  const int lcol = (t & 15) * 4;         // staging col
  const int frow = lane & 15;            // MFMA frag row
  const int fk   = (lane >> 4) * 8;      // MFMA frag k offset

  // ---------------- Phase A: G = X X^T ----------------
  for (int ch = 0; ch < 8; ++ch) {
    __syncthreads();                     // protect staging reuse
#pragma unroll
    for (int p = 0; p < 4; ++p) {
      const int r = lrow + 16 * p;
      const f32x4 v = *(const f32x4*)(X + (size_t)r * NCOL + ch * 64 + lcol);
      u16x4 hv, lv;
#pragma unroll
      for (int j = 0; j < 4; ++j) {
        const unsigned short h = bf16h(v[j]);
        hv[j] = h;
        lv[j] = bf16h(v[j] - bf16f(h));
      }
      *(u16x4*)&U.s.Hs[r][lcol] = hv;
      *(u16x4*)&U.s.Ls[r][lcol] = lv;
    }
    __syncthreads();
#pragma unroll
    for (int s = 0; s < 2; ++s) {
      const int kc = s * 32 + fk;
      const s16x8 ha = *(const s16x8*)&U.s.Hs[16 * w + frow][kc];
      const s16x8 la = *(const s16x8*)&U.s.Ls[16 * w + frow][kc];
#pragma unroll
      for (int bt = 0; bt < 4; ++bt) {
        const s16x8 hb = *(const s16x8*)&U.s.Hs[16 * bt + frow][kc];
        const s16x8 lb = *(const s16x8*)&U.s.Ls[16 * bt + frow][kc];
        acc[bt] = __builtin_amdgcn_mfma_f32_16x16x32_bf16(ha, hb, acc[bt], 0, 0, 0);
        acc[bt] = __builtin_amdgcn_mfma_f32_16x16x32_bf16(ha, lb, acc[bt], 0, 0, 0);
        acc[bt] = __builtin_amdgcn_mfma_f32_16x16x32_bf16(la, hb, acc[bt], 0, 0, 0);
      }
    }
  }
  __syncthreads();                       // all staging reads done before overlay

  // write G into LDS (C/D layout: col = lane&15, row = (lane>>4)*4 + reg)
  {
    const int drow = (lane >> 4) * 4;
    const int dcol = lane & 15;
#pragma unroll
    for (int bt = 0; bt < 4; ++bt)
#pragma unroll
      for (int rr = 0; rr < 4; ++rr)
        U.GW[16 * w + drow + rr][16 * bt + dcol] = acc[bt][rr];
  }
  __syncthreads();

  if (t >= 64) return;                   // waves 1-3 done; wave 0 solves alone
  const int j = t;                       // lane = row (LDL) / column (TI)

  // ---------------- Phase B: wave-0 register solve ----------------
  // W-row j of G into registers (16B-aligned: stride 68 f32 = 272 B)
  float wr[64];
#pragma unroll
  for (int c = 0; c < 16; ++c) {
    const f32x4 v = *(const f32x4*)&U.GW[j][4 * c];
    wr[4 * c + 0] = v[0]; wr[4 * c + 1] = v[1]; wr[4 * c + 2] = v[2]; wr[4 * c + 3] = v[3];
  }

  // LDL: W[j][k] -= sum_{m<k} Cs[k][m]*W[j][m]; Cs[j][k] = W[j][k]/n_k.
  // Cs overwrites GW column k at step k (wr holds the private row copy).
  {
    const float nk = __shfl(wr[0], 0);
    const float inv = 1.0f / nk;
    U.GW[j][0] = wr[0] * inv;
    if (j == 0) ISN[0] = sqrtf(inv);
  }
#pragma unroll
  for (int k = 1; k < 64; ++k) {
    float a0 = 0.f, a1 = 0.f, a2 = 0.f, a3 = 0.f;
    const int K4 = k >> 2;
#pragma unroll
    for (int m4 = 0; m4 < K4; ++m4) {
      const f32x4 c4 = *(const f32x4*)&U.GW[k][4 * m4];   // uniform broadcast
      a0 += c4[0] * wr[4 * m4 + 0];
      a1 += c4[1] * wr[4 * m4 + 1];
      a2 += c4[2] * wr[4 * m4 + 2];
      a3 += c4[3] * wr[4 * m4 + 3];
    }
#pragma unroll
    for (int m = 4 * K4; m < k; ++m) a0 += U.GW[k][m] * wr[m];
    wr[k] -= (a0 + a1) + (a2 + a3);
    const float nk = __shfl(wr[k], k);
    const float inv = 1.0f / nk;
    U.GW[j][k] = wr[k] * inv;
    if (j == 0) ISN[k] = sqrtf(inv);
  }

  // TI: lane j owns column j in registers; ti[i] = d(i,j) - sum Cs[i][m]*ti[m]
  float ti[64];
  ti[0] = (j == 0) ? 1.0f : 0.0f;
#pragma unroll
  for (int i = 1; i < 64; ++i) {
    float a0 = 0.f, a1 = 0.f, a2 = 0.f, a3 = 0.f;
    const int I4 = i >> 2;
#pragma unroll
    for (int m4 = 0; m4 < I4; ++m4) {
      const f32x4 c4 = *(const f32x4*)&U.GW[i][4 * m4];   // uniform broadcast
      a0 += c4[0] * ti[4 * m4 + 0];
      a1 += c4[1] * ti[4 * m4 + 1];
      a2 += c4[2] * ti[4 * m4 + 2];
      a3 += c4[3] * ti[4 * m4 + 3];
    }
#pragma unroll
    for (int m = 4 * I4; m < i; ++m) a0 += U.GW[i][m] * ti[m];
    ti[i] = ((i == j) ? 1.0f : 0.0f) - ((a0 + a1) + (a2 + a3));
  }

  // transpose T into LDS (overlay over dead Cs; single wave -> no barrier,
  // compiler orders ds_write->ds_read via lgkmcnt), then coalesced copy out.
  unsigned short* __restrict__ TL = (unsigned short*)&U.GW[0][0];
#pragma unroll
  for (int i = 0; i < 64; ++i) {
    const float tf = ISN[i] * ti[i];
    const unsigned short h = bf16h(tf);
    TL[i * 64 + j] = h;                            // Th plane
    TL[4096 + i * 64 + j] = bf16h(tf - bf16f(h));  // Tl plane
  }
  float* __restrict__ slot = outbuf + (size_t)b * SLOT;
  const unsigned int* __restrict__ TL32 = (const unsigned int*)TL;
  unsigned int* __restrict__ slotT = (unsigned int*)slot;
#pragma unroll
  for (int q = 0; q < 64; ++q) slotT[j + 64 * q] = TL32[j + 64 * q];
}

// Kernel 2: out = T * X per batch, pure MFMA.  T fragments loaded directly
// from global (planar slot head, L2/L3-hot).  17.4 KB LDS.
__global__ __launch_bounds__(256) void gs_apply_kernel(const float* __restrict__ x,
                                                       float* __restrict__ outbuf)
{
  __shared__ unsigned short XTh[64][68];
  __shared__ unsigned short XTl[64][68];

  const int b = blockIdx.x;
  const int t = threadIdx.x;
  const int lane = t & 63;
  const int w = t >> 6;

  float* __restrict__ slot = outbuf + (size_t)b * SLOT;
  const unsigned short* __restrict__ slotU = (const unsigned short*)slot;

  const int frow = lane & 15;
  const int fk = (lane >> 4) * 8;

  // A-operand fragments straight from global: planar Th/Tl rows
  s16x8 tah[2], tal[2];
#pragma unroll
  for (int ks = 0; ks < 2; ++ks) {
    tah[ks] = *(const s16x8*)&slotU[(16 * w + frow) * 64 + ks * 32 + fk];
    tal[ks] = *(const s16x8*)&slotU[4096 + (16 * w + frow) * 64 + ks * 32 + fk];
  }
  __syncthreads();   // vmcnt drained at barrier: T loads landed before any store

  const float* __restrict__ X = x + (size_t)b * SLOT;
  const int lrow4 = (t >> 4) * 4;
  const int lcol4 = (t & 15) * 4;

  for (int ch = 0; ch < 8; ++ch) {
    if (ch) __syncthreads();             // protect XT from prev-chunk readers
    float vr[4][4];
#pragma unroll
    for (int p = 0; p < 4; ++p) {
      const f32x4 v = *(const f32x4*)(X + (size_t)(lrow4 + p) * NCOL + ch * 64 + lcol4);
      vr[p][0] = v[0]; vr[p][1] = v[1]; vr[p][2] = v[2]; vr[p][3] = v[3];
    }
#pragma unroll
    for (int jj = 0; jj < 4; ++jj) {
      u16x4 hv, lv;
#pragma unroll
      for (int p = 0; p < 4; ++p) {
        const unsigned short h = bf16h(vr[p][jj]);
        hv[p] = h;
        lv[p] = bf16h(vr[p][jj] - bf16f(h));
      }
      *(u16x4*)&XTh[lcol4 + jj][lrow4] = hv;
      *(u16x4*)&XTl[lcol4 + jj][lrow4] = lv;
    }
    __syncthreads();

    f32x4 oacc[4];
#pragma unroll
    for (int q = 0; q < 4; ++q) { oacc[q][0] = 0.f; oacc[q][1] = 0.f; oacc[q][2] = 0.f; oacc[q][3] = 0.f; }

#pragma unroll
    for (int ks = 0; ks < 2; ++ks) {
      const int kc = ks * 32 + fk;
#pragma unroll
      for (int ct = 0; ct < 4; ++ct) {
        const s16x8 xbh = ld8(&XTh[ct * 16 + frow][kc]);
        const s16x8 xbl = ld8(&XTl[ct * 16 + frow][kc]);
        oacc[ct] = __builtin_amdgcn_mfma_f32_16x16x32_bf16(tah[ks], xbh, oacc[ct], 0, 0, 0);
        oacc[ct] = __builtin_amdgcn_mfma_f32_16x16x32_bf16(tah[ks], xbl, oacc[ct], 0, 0, 0);
        oacc[ct] = __builtin_amdgcn_mfma_f32_16x16x32_bf16(tal[ks], xbh, oacc[ct], 0, 0, 0);
      }
    }

    const int drow = (lane >> 4) * 4;
    const int dcol = lane & 15;
#pragma unroll
    for (int ct = 0; ct < 4; ++ct)
#pragma unroll
      for (int rr = 0; rr < 4; ++rr)
        slot[(size_t)(16 * w + drow + rr) * NCOL + ch * 64 + ct * 16 + dcol] = oacc[ct][rr];
  }
}

extern "C" void kernel_launch(void* const* d_in, const int* in_sizes, int n_in,
                              void* d_out, int out_size, void* d_ws, size_t ws_size,
                              hipStream_t stream) {
  const float* x = (const float*)d_in[0];
  float* out = (float*)d_out;
  gs_gram_solve_kernel<<<NBATCH, 256, 0, stream>>>(x, out);
  gs_apply_kernel<<<NBATCH, 256, 0, stream>>>(x, out);
}

// Round 11
// 136.256 us; speedup vs baseline: 1.3077x; 1.3077x over previous
//
#include <hip/hip_runtime.h>
#include <hip/hip_bf16.h>
#include <cmath>

typedef __attribute__((ext_vector_type(4))) float f32x4;
typedef __attribute__((ext_vector_type(8))) short s16x8;
typedef __attribute__((ext_vector_type(4))) short s16x4;
typedef __attribute__((ext_vector_type(4))) unsigned short u16x4;

static constexpr int NCOL = 512;    // L
static constexpr int NBATCH = 1024; // 32*32
static constexpr int SLOT = 64 * NCOL;     // floats per batch slot

__device__ inline unsigned short bf16h(float f) {
  return __builtin_bit_cast(unsigned short, __float2bfloat16(f));
}
__device__ inline float bf16f(unsigned short h) {
  unsigned u = ((unsigned)h) << 16;
  return __builtin_bit_cast(float, u);
}

// 8B-aligned s16x8 load (XT rows at stride 68 ushorts are only 8B-aligned)
__device__ inline s16x8 ld8(const unsigned short* p) {
  const s16x4 a = *(const s16x4*)(p);
  const s16x4 b = *(const s16x4*)(p + 4);
  s16x8 r;
  r[0]=a[0]; r[1]=a[1]; r[2]=a[2]; r[3]=a[3];
  r[4]=b[0]; r[5]=b[1]; r[6]=b[2]; r[7]=b[3];
  return r;
}

// bf16 hi/lo staging buffers (gram phase) overlaid by G/Cs f32 matrix
// (solve phase) -> T hi/lo planes (emit).  18432 B total.
union GramLds {
  struct { unsigned short Hs[64][72]; unsigned short Ls[64][72]; } s; // 18432 B
  float GW[64][68];                                                  // 17408 B
};

// Kernel 1: per-batch G = X X^T via bf16 hi/lo MFMA (G kept in LDS), then
// waves 1-3 exit and wave 0 runs the register LDL -> scaled coeffs Cs (in
// place over G) -> register triangular inverse -> emits
// T = diag(1/sqrt(n)) * (I+C)^{-1} PLANAR bf16 hi/lo to the slot head.
// NOTE: plain __launch_bounds__(256) — declaring a min-waves target made the
// compiler cap VGPR at 64 and spill the 128-float solve state (round 10:
// FETCH +11 MB, 142 us).  Round 8 measured this code at 124 VGPR, no spill.
__global__ __launch_bounds__(256) void gs_gram_solve_kernel(const float* __restrict__ x,
                                                            float* __restrict__ outbuf)
{
  __shared__ GramLds U;
  __shared__ float ISN[64];

  const int b = blockIdx.x;
  const int t = threadIdx.x;
  const int lane = t & 63;
  const int w = t >> 6;

  const float* __restrict__ X = x + (size_t)b * SLOT;

  f32x4 acc[4];
#pragma unroll
  for (int q = 0; q < 4; ++q) { acc[q][0] = 0.f; acc[q][1] = 0.f; acc[q][2] = 0.f; acc[q][3] = 0.f; }

  const int lrow = t >> 4;               // 0..15 staging row base
  const int lcol = (t & 15) * 4;         // staging col
  const int frow = lane & 15;            // MFMA frag row
  const int fk   = (lane >> 4) * 8;      // MFMA frag k offset

  // ---------------- Phase A: G = X X^T ----------------
  for (int ch = 0; ch < 8; ++ch) {
    __syncthreads();                     // protect staging reuse
#pragma unroll
    for (int p = 0; p < 4; ++p) {
      const int r = lrow + 16 * p;
      const f32x4 v = *(const f32x4*)(X + (size_t)r * NCOL + ch * 64 + lcol);
      u16x4 hv, lv;
#pragma unroll
      for (int j = 0; j < 4; ++j) {
        const unsigned short h = bf16h(v[j]);
        hv[j] = h;
        lv[j] = bf16h(v[j] - bf16f(h));
      }
      *(u16x4*)&U.s.Hs[r][lcol] = hv;
      *(u16x4*)&U.s.Ls[r][lcol] = lv;
    }
    __syncthreads();
#pragma unroll
    for (int s = 0; s < 2; ++s) {
      const int kc = s * 32 + fk;
      const s16x8 ha = *(const s16x8*)&U.s.Hs[16 * w + frow][kc];
      const s16x8 la = *(const s16x8*)&U.s.Ls[16 * w + frow][kc];
#pragma unroll
      for (int bt = 0; bt < 4; ++bt) {
        const s16x8 hb = *(const s16x8*)&U.s.Hs[16 * bt + frow][kc];
        const s16x8 lb = *(const s16x8*)&U.s.Ls[16 * bt + frow][kc];
        acc[bt] = __builtin_amdgcn_mfma_f32_16x16x32_bf16(ha, hb, acc[bt], 0, 0, 0);
        acc[bt] = __builtin_amdgcn_mfma_f32_16x16x32_bf16(ha, lb, acc[bt], 0, 0, 0);
        acc[bt] = __builtin_amdgcn_mfma_f32_16x16x32_bf16(la, hb, acc[bt], 0, 0, 0);
      }
    }
  }
  __syncthreads();                       // all staging reads done before overlay

  // write G into LDS (C/D layout: col = lane&15, row = (lane>>4)*4 + reg)
  {
    const int drow = (lane >> 4) * 4;
    const int dcol = lane & 15;
#pragma unroll
    for (int bt = 0; bt < 4; ++bt)
#pragma unroll
      for (int rr = 0; rr < 4; ++rr)
        U.GW[16 * w + drow + rr][16 * bt + dcol] = acc[bt][rr];
  }
  __syncthreads();

  if (t >= 64) return;                   // waves 1-3 done; wave 0 solves alone
  const int j = t;                       // lane = row (LDL) / column (TI)

  // ---------------- Phase B: wave-0 register solve ----------------
  // W-row j of G into registers (16B-aligned: stride 68 f32 = 272 B)
  float wr[64];
#pragma unroll
  for (int c = 0; c < 16; ++c) {
    const f32x4 v = *(const f32x4*)&U.GW[j][4 * c];
    wr[4 * c + 0] = v[0]; wr[4 * c + 1] = v[1]; wr[4 * c + 2] = v[2]; wr[4 * c + 3] = v[3];
  }

  // LDL: W[j][k] -= sum_{m<k} Cs[k][m]*W[j][m]; Cs[j][k] = W[j][k]/n_k.
  // Cs overwrites GW column k at step k (wr holds the private row copy).
  {
    const float nk = __shfl(wr[0], 0);
    const float inv = 1.0f / nk;
    U.GW[j][0] = wr[0] * inv;
    if (j == 0) ISN[0] = sqrtf(inv);
  }
#pragma unroll
  for (int k = 1; k < 64; ++k) {
    float a0 = 0.f, a1 = 0.f, a2 = 0.f, a3 = 0.f;
    const int K4 = k >> 2;
#pragma unroll
    for (int m4 = 0; m4 < K4; ++m4) {
      const f32x4 c4 = *(const f32x4*)&U.GW[k][4 * m4];   // uniform broadcast
      a0 += c4[0] * wr[4 * m4 + 0];
      a1 += c4[1] * wr[4 * m4 + 1];
      a2 += c4[2] * wr[4 * m4 + 2];
      a3 += c4[3] * wr[4 * m4 + 3];
    }
#pragma unroll
    for (int m = 4 * K4; m < k; ++m) a0 += U.GW[k][m] * wr[m];
    wr[k] -= (a0 + a1) + (a2 + a3);
    const float nk = __shfl(wr[k], k);
    const float inv = 1.0f / nk;
    U.GW[j][k] = wr[k] * inv;
    if (j == 0) ISN[k] = sqrtf(inv);
  }

  // TI: lane j owns column j in registers; ti[i] = d(i,j) - sum Cs[i][m]*ti[m]
  float ti[64];
  ti[0] = (j == 0) ? 1.0f : 0.0f;
#pragma unroll
  for (int i = 1; i < 64; ++i) {
    float a0 = 0.f, a1 = 0.f, a2 = 0.f, a3 = 0.f;
    const int I4 = i >> 2;
#pragma unroll
    for (int m4 = 0; m4 < I4; ++m4) {
      const f32x4 c4 = *(const f32x4*)&U.GW[i][4 * m4];   // uniform broadcast
      a0 += c4[0] * ti[4 * m4 + 0];
      a1 += c4[1] * ti[4 * m4 + 1];
      a2 += c4[2] * ti[4 * m4 + 2];
      a3 += c4[3] * ti[4 * m4 + 3];
    }
#pragma unroll
    for (int m = 4 * I4; m < i; ++m) a0 += U.GW[i][m] * ti[m];
    ti[i] = ((i == j) ? 1.0f : 0.0f) - ((a0 + a1) + (a2 + a3));
  }

  // transpose T into LDS (overlay over dead Cs; single wave -> no barrier,
  // compiler orders ds_write->ds_read via lgkmcnt), then coalesced copy out.
  unsigned short* __restrict__ TL = (unsigned short*)&U.GW[0][0];
#pragma unroll
  for (int i = 0; i < 64; ++i) {
    const float tf = ISN[i] * ti[i];
    const unsigned short h = bf16h(tf);
    TL[i * 64 + j] = h;                            // Th plane
    TL[4096 + i * 64 + j] = bf16h(tf - bf16f(h));  // Tl plane
  }
  float* __restrict__ slot = outbuf + (size_t)b * SLOT;
  const unsigned int* __restrict__ TL32 = (const unsigned int*)TL;
  unsigned int* __restrict__ slotT = (unsigned int*)slot;
#pragma unroll
  for (int q = 0; q < 64; ++q) slotT[j + 64 * q] = TL32[j + 64 * q];
}

// Kernel 2: out = T * X per batch, pure MFMA.  T fragments loaded directly
// from global (planar slot head, L2/L3-hot).  17.4 KB LDS.
__global__ __launch_bounds__(256) void gs_apply_kernel(const float* __restrict__ x,
                                                       float* __restrict__ outbuf)
{
  __shared__ unsigned short XTh[64][68];
  __shared__ unsigned short XTl[64][68];

  const int b = blockIdx.x;
  const int t = threadIdx.x;
  const int lane = t & 63;
  const int w = t >> 6;

  float* __restrict__ slot = outbuf + (size_t)b * SLOT;
  const unsigned short* __restrict__ slotU = (const unsigned short*)slot;

  const int frow = lane & 15;
  const int fk = (lane >> 4) * 8;

  // A-operand fragments straight from global: planar Th/Tl rows
  s16x8 tah[2], tal[2];
#pragma unroll
  for (int ks = 0; ks < 2; ++ks) {
    tah[ks] = *(const s16x8*)&slotU[(16 * w + frow) * 64 + ks * 32 + fk];
    tal[ks] = *(const s16x8*)&slotU[4096 + (16 * w + frow) * 64 + ks * 32 + fk];
  }
  __syncthreads();   // vmcnt drained at barrier: T loads landed before any store

  const float* __restrict__ X = x + (size_t)b * SLOT;
  const int lrow4 = (t >> 4) * 4;
  const int lcol4 = (t & 15) * 4;

  for (int ch = 0; ch < 8; ++ch) {
    if (ch) __syncthreads();             // protect XT from prev-chunk readers
    float vr[4][4];
#pragma unroll
    for (int p = 0; p < 4; ++p) {
      const f32x4 v = *(const f32x4*)(X + (size_t)(lrow4 + p) * NCOL + ch * 64 + lcol4);
      vr[p][0] = v[0]; vr[p][1] = v[1]; vr[p][2] = v[2]; vr[p][3] = v[3];
    }
#pragma unroll
    for (int jj = 0; jj < 4; ++jj) {
      u16x4 hv, lv;
#pragma unroll
      for (int p = 0; p < 4; ++p) {
        const unsigned short h = bf16h(vr[p][jj]);
        hv[p] = h;
        lv[p] = bf16h(vr[p][jj] - bf16f(h));
      }
      *(u16x4*)&XTh[lcol4 + jj][lrow4] = hv;
      *(u16x4*)&XTl[lcol4 + jj][lrow4] = lv;
    }
    __syncthreads();

    f32x4 oacc[4];
#pragma unroll
    for (int q = 0; q < 4; ++q) { oacc[q][0] = 0.f; oacc[q][1] = 0.f; oacc[q][2] = 0.f; oacc[q][3] = 0.f; }

#pragma unroll
    for (int ks = 0; ks < 2; ++ks) {
      const int kc = ks * 32 + fk;
#pragma unroll
      for (int ct = 0; ct < 4; ++ct) {
        const s16x8 xbh = ld8(&XTh[ct * 16 + frow][kc]);
        const s16x8 xbl = ld8(&XTl[ct * 16 + frow][kc]);
        oacc[ct] = __builtin_amdgcn_mfma_f32_16x16x32_bf16(tah[ks], xbh, oacc[ct], 0, 0, 0);
        oacc[ct] = __builtin_amdgcn_mfma_f32_16x16x32_bf16(tah[ks], xbl, oacc[ct], 0, 0, 0);
        oacc[ct] = __builtin_amdgcn_mfma_f32_16x16x32_bf16(tal[ks], xbh, oacc[ct], 0, 0, 0);
      }
    }

    const int drow = (lane >> 4) * 4;
    const int dcol = lane & 15;
#pragma unroll
    for (int ct = 0; ct < 4; ++ct)
#pragma unroll
      for (int rr = 0; rr < 4; ++rr)
        slot[(size_t)(16 * w + drow + rr) * NCOL + ch * 64 + ct * 16 + dcol] = oacc[ct][rr];
  }
}

extern "C" void kernel_launch(void* const* d_in, const int* in_sizes, int n_in,
                              void* d_out, int out_size, void* d_ws, size_t ws_size,
                              hipStream_t stream) {
  const float* x = (const float*)d_in[0];
  float* out = (float*)d_out;
  gs_gram_solve_kernel<<<NBATCH, 256, 0, stream>>>(x, out);
  gs_apply_kernel<<<NBATCH, 256, 0, stream>>>(x, out);
}